// Round 1
// baseline (833.582 us; speedup 1.0000x reference)
//
#include <hip/hip_runtime.h>

typedef _Float16 half_t;
typedef __attribute__((ext_vector_type(8))) _Float16 half8;
typedef __attribute__((ext_vector_type(4))) _Float16 half4v;
typedef __attribute__((ext_vector_type(4))) float f32x4;

#define MFMA16(a,b,c) __builtin_amdgcn_mfma_f32_16x16x32_f16((a),(b),(c),0,0,0)

__device__ __forceinline__ void gld_lds16(const half_t* g, half_t* l){
    __builtin_amdgcn_global_load_lds((__attribute__((address_space(1))) void*)(g),
                                     (__attribute__((address_space(3))) void*)(l), 16, 0, 0);
}

// ---------------- fp32 -> fp16 convert ----------------
__global__ __launch_bounds__(256) void cvt_k(const float* __restrict__ s, half_t* __restrict__ d, int n4){
    int i = blockIdx.x * 256 + threadIdx.x;
    if (i < n4){
        float4 v = ((const float4*)s)[i];
        half4v h = { (half_t)v.x, (half_t)v.y, (half_t)v.z, (half_t)v.w };
        ((half4v*)d)[i] = h;
    }
}

__global__ __launch_bounds__(256) void cvtw_k(const float* __restrict__ w0, const float* __restrict__ w1,
                                              const float* __restrict__ w2, const float* __restrict__ w3,
                                              half_t* __restrict__ dst){
    const float* srcs[4] = {w0, w1, w2, w3};
    const float* s = srcs[blockIdx.y];
    int i = blockIdx.x * 256 + threadIdx.x;
    float4 v = ((const float4*)s)[i];
    half4v h = { (half_t)v.x, (half_t)v.y, (half_t)v.z, (half_t)v.w };
    ((half4v*)(dst))[(size_t)blockIdx.y * 1048576 + i] = h;
}

// ---------------- NT GEMM: C[m,n] = sum_k A[m,k]*B[n,k] ----------------
__global__ __launch_bounds__(256) void gemm_nt(const half_t* __restrict__ A, const half_t* __restrict__ B,
                                               half_t* __restrict__ Qw, half_t* __restrict__ Kw,
                                               half_t* __restrict__ Vt, float* __restrict__ Co, int kind){
    const int tid  = threadIdx.x;
    const int lane = tid & 63;
    const int w    = lane >> 4;
    const int l15  = lane & 15;
    const int l7   = lane & 7;
    const int wav  = tid >> 6;
    const int wm   = (wav >> 1) * 64;
    const int wn   = (wav & 1) * 64;
    const int bm   = blockIdx.x;
    const int bn   = blockIdx.y;
    const int KD   = 2048;

    __shared__ __align__(16) half_t smem[16384];
    half_t* As = smem;
    half_t* Bs = smem + 8192;

    f32x4 acc[4][4] = {};

    const half_t* Ab = A + (size_t)bm * 128 * KD;
    const half_t* Bb = B + (size_t)bn * 128 * KD;

    for (int k0 = 0; k0 < KD; k0 += 64){
#pragma unroll
        for (int i = 0; i < 4; i++){
            int c = tid + i*256;
            int r = c >> 3, p = c & 7;
            gld_lds16(Ab + (size_t)r*KD + k0 + ((p ^ (r&7)) << 3), As + c*8);
        }
#pragma unroll
        for (int i = 0; i < 4; i++){
            int c = tid + i*256;
            int r = c >> 3, p = c & 7;
            gld_lds16(Bb + (size_t)r*KD + k0 + ((p ^ (r&7)) << 3), Bs + c*8);
        }
        __syncthreads();
#pragma unroll
        for (int ks = 0; ks < 2; ks++){
            half8 af[4], bf[4];
#pragma unroll
            for (int mi = 0; mi < 4; mi++)
                af[mi] = *(const half8*)(As + (wm + mi*16 + l15)*64 + (((ks*4 + w) ^ l7) << 3));
#pragma unroll
            for (int ni = 0; ni < 4; ni++)
                bf[ni] = *(const half8*)(Bs + (wn + ni*16 + l15)*64 + (((ks*4 + w) ^ l7) << 3));
#pragma unroll
            for (int mi = 0; mi < 4; mi++)
#pragma unroll
                for (int ni = 0; ni < 4; ni++)
                    acc[mi][ni] = MFMA16(af[mi], bf[ni], acc[mi][ni]);
        }
        __syncthreads();
    }

    const int rbase = wm + w*4;
    const int cbase = wn + l15;

    if (kind == 0){
        const int which = bn >> 4;
        const int nb = (bn & 15) * 128;
        if (which < 2){
            half_t* dst = which ? Kw : Qw;
#pragma unroll
            for (int mi = 0; mi < 4; mi++)
#pragma unroll
                for (int ni = 0; ni < 4; ni++)
#pragma unroll
                    for (int r = 0; r < 4; r++){
                        int m = bm*128 + rbase + mi*16 + r;
                        int n = nb + cbase + ni*16;
                        dst[(((size_t)(m>>11)*16 + (n>>7))*2048 + (m&2047))*128 + (n&127)] = (half_t)acc[mi][ni][r];
                    }
        } else {
#pragma unroll
            for (int mi = 0; mi < 4; mi++)
#pragma unroll
                for (int ni = 0; ni < 4; ni++){
                    int m0 = bm*128 + rbase + mi*16;
                    int n  = nb + cbase + ni*16;
                    half4v h = {(half_t)acc[mi][ni][0], (half_t)acc[mi][ni][1],
                                (half_t)acc[mi][ni][2], (half_t)acc[mi][ni][3]};
                    *(half4v*)(Vt + (((size_t)(m0>>11)*16 + (n>>7))*128 + (n&127))*2048 + (m0&2047)) = h;
                }
        }
    } else {
#pragma unroll
        for (int mi = 0; mi < 4; mi++)
#pragma unroll
            for (int ni = 0; ni < 4; ni++)
#pragma unroll
                for (int r = 0; r < 4; r++){
                    int m = bm*128 + rbase + mi*16 + r;
                    int n = bn*128 + cbase + ni*16;
                    Co[(size_t)m*2048 + n] = acc[mi][ni][r];
                }
    }
}

// ---------------- RoPE in-place on Q/K [b*16+h][s][128] ----------------
__global__ __launch_bounds__(256) void rope_k(half_t* __restrict__ Qw, half_t* __restrict__ Kw,
                                              const float* __restrict__ cs, const float* __restrict__ sn){
    int t  = blockIdx.x * 256 + threadIdx.x;
    int d  = t & 63;
    int s  = (t >> 6) & 2047;
    int bh = t >> 17;
    float c  = cs[s*64 + d];
    float si = sn[s*64 + d];
    size_t base = ((size_t)bh*2048 + s)*128 + d;
    float q1 = (float)Qw[base], q2 = (float)Qw[base+64];
    Qw[base]    = (half_t)(q1*c - q2*si);
    Qw[base+64] = (half_t)(q1*si + q2*c);
    float k1 = (float)Kw[base], k2 = (float)Kw[base+64];
    Kw[base]    = (half_t)(k1*c - k2*si);
    Kw[base+64] = (half_t)(k1*si + k2*c);
}

// ---------------- Flash attention, S^T formulation, split-K=2 ----------------
// Q[bh][s][128], K[bh][s][128], Vt[bh][128][s].
// blockIdx.x: (bx&15)=q-tile, (bx>>4)=key-half. Each block does 16 of 32 kt tiles
// and writes a normalized partial O (f16, AO layout) + per-row m,l (f32, log2 domain).
// 2048 half-size blocks kill the 256-block tail round (was 768+256 @ 3 blocks/CU).
__global__ __launch_bounds__(256, 3) void attn_k(const half_t* __restrict__ Q, const half_t* __restrict__ K,
                                                 const half_t* __restrict__ Vt, half_t* __restrict__ PO0,
                                                 half_t* __restrict__ PO1, float* __restrict__ ML){
    const int tid  = threadIdx.x;
    const int lane = tid & 63;
    const int w    = lane >> 4;
    const int l15  = lane & 15;
    const int l7   = lane & 7;
    const int wav  = tid >> 6;
    const int qt   = blockIdx.x & 15;   // 16 q-tiles of 128
    const int kh   = blockIdx.x >> 4;   // key half: kt in [kh*16, kh*16+16)
    const int bh   = blockIdx.y;        // 64

    __shared__ __align__(16) half_t smem[8192 + 8192 + 4*2304];
    half_t* Ks = smem;
    half_t* Vs = smem + 8192;
    half_t* Ps = smem + 16384 + wav*2304;
    half_t* Ob = smem + wav*4096;

    const half_t* Qb = Q + ((size_t)bh*2048 + qt*128 + wav*32)*128;
    half8 aq[2][4];
#pragma unroll
    for (int qi = 0; qi < 2; qi++)
#pragma unroll
        for (int ks = 0; ks < 4; ks++)
            aq[qi][ks] = *(const half8*)(Qb + (qi*16 + l15)*128 + ks*32 + w*8);

    f32x4 oacc[8][2] = {};
    float m_[2] = {-1e30f, -1e30f};
    float l_[2] = {0.0f, 0.0f};

    const float SSC = 0.08838834764831845f * 1.4426950408889634f;  // 1/sqrt(128) * log2(e)

    const int kt0 = kh << 4;
    for (int kt = kt0; kt < kt0 + 16; kt++){
        const half_t* Kb = K  + ((size_t)bh*2048 + kt*64)*128;
        const half_t* Vb = Vt + (size_t)bh*128*2048 + kt*64;
        __syncthreads();
#pragma unroll
        for (int i = 0; i < 4; i++){
            int c = tid + i*256;
            int key = c >> 4, pc = c & 15;
            gld_lds16(Kb + key*128 + ((pc ^ (key&7)) << 3), Ks + c*8);
        }
#pragma unroll
        for (int i = 0; i < 4; i++){
            int c = tid + i*256;
            int d = c >> 3, pc = c & 7;
            gld_lds16(Vb + (size_t)d*2048 + ((pc ^ (d&7)) << 3), Vs + c*8);
        }
        __syncthreads();

        // S^T = K @ Q^T : rows=key (4 tiles), cols=q (2 tiles)
        f32x4 sacc[4][2] = {};
#pragma unroll
        for (int ks = 0; ks < 4; ks++){
#pragma unroll
            for (int t = 0; t < 4; t++){
                half8 kf = *(const half8*)(Ks + (t*16 + l15)*128 + (((ks*4 + w) ^ l7) << 3));
                sacc[t][0] = MFMA16(kf, aq[0][ks], sacc[t][0]);
                sacc[t][1] = MFMA16(kf, aq[1][ks], sacc[t][1]);
            }
        }

        // online softmax per q-column; defer-max: skip rescale when no column max grew (exact)
#pragma unroll
        for (int qi = 0; qi < 2; qi++){
            float mx = sacc[0][qi][0];
#pragma unroll
            for (int t = 0; t < 4; t++)
#pragma unroll
                for (int r = 0; r < 4; r++) mx = fmaxf(mx, sacc[t][qi][r]);
            mx = fmaxf(mx, __shfl_xor(mx, 16));
            mx = fmaxf(mx, __shfl_xor(mx, 32));
            float mxs = mx * SSC;
            unsigned long long upd = __ballot(mxs > m_[qi]);
            if (upd){
                float mn    = fmaxf(m_[qi], mxs);
                float alpha = exp2f(m_[qi] - mn);
                m_[qi] = mn;
                l_[qi] *= alpha;
#pragma unroll
                for (int t = 0; t < 8; t++)
#pragma unroll
                    for (int r = 0; r < 4; r++) oacc[t][qi][r] *= alpha;
            }
            float mq = m_[qi];
            float sum = 0.0f;
#pragma unroll
            for (int t = 0; t < 4; t++){
                float p0 = exp2f(sacc[t][qi][0]*SSC - mq);
                float p1 = exp2f(sacc[t][qi][1]*SSC - mq);
                float p2 = exp2f(sacc[t][qi][2]*SSC - mq);
                float p3 = exp2f(sacc[t][qi][3]*SSC - mq);
                sum += (p0 + p1) + (p2 + p3);
                half4v hv = {(half_t)p0, (half_t)p1, (half_t)p2, (half_t)p3};
                *(half4v*)(Ps + (qi*16 + l15)*72 + t*16 + w*4) = hv;
            }
            sum += __shfl_xor(sum, 16);
            sum += __shfl_xor(sum, 32);
            l_[qi] += sum;
        }

        // O^T += V^T @ P^T
#pragma unroll
        for (int c2 = 0; c2 < 2; c2++){
            half8 pf0 = *(const half8*)(Ps + l15*72        + c2*32 + w*8);
            half8 pf1 = *(const half8*)(Ps + (16 + l15)*72 + c2*32 + w*8);
#pragma unroll
            for (int t = 0; t < 8; t++){
                half8 vf = *(const half8*)(Vs + (t*16 + l15)*64 + (((c2*4 + w) ^ l7) << 3));
                oacc[t][0] = MFMA16(vf, pf0, oacc[t][0]);
                oacc[t][1] = MFMA16(vf, pf1, oacc[t][1]);
            }
        }
    }

    // per-row m,l for the merge (replicated across quads; w==0 writes)
    if (w == 0){
#pragma unroll
        for (int qi = 0; qi < 2; qi++){
            int srow = bh*2048 + qt*128 + wav*32 + qi*16 + l15;
            ML[(size_t)(kh*2)*131072     + srow] = m_[qi];
            ML[(size_t)(kh*2 + 1)*131072 + srow] = l_[qi];
        }
    }

    // epilogue: transpose O^T -> O through LDS, coalesced global stores of normalized partial
    float inv[2] = {1.0f / l_[0], 1.0f / l_[1]};
    half_t* DST = kh ? PO1 : PO0;
    __syncthreads();
#pragma unroll
    for (int t = 0; t < 8; t++)
#pragma unroll
        for (int qi = 0; qi < 2; qi++){
            int q  = qi*16 + l15;
            int c8 = t*2 + (w>>1);
            int pc = c8 ^ l7;
            half4v hv = {(half_t)(oacc[t][qi][0]*inv[qi]), (half_t)(oacc[t][qi][1]*inv[qi]),
                         (half_t)(oacc[t][qi][2]*inv[qi]), (half_t)(oacc[t][qi][3]*inv[qi])};
            *(half4v*)(Ob + q*128 + pc*8 + (w&1)*4) = hv;
        }
    const int b = bh >> 4, h = bh & 15;
#pragma unroll
    for (int it = 0; it < 8; it++){
        int q  = it*4 + w;
        half8 rd = *(const half8*)(Ob + q*128 + ((l15 ^ (q&7)) << 3));
        int s = qt*128 + wav*32 + q;
        *(half8*)(DST + ((size_t)(b*2048 + s))*2048 + h*128 + l15*8) = rd;
    }
}

// ---------------- merge the two key-half partials: exact softmax combine ----------------
__global__ __launch_bounds__(256) void merge_k(const half_t* __restrict__ P0, const half_t* __restrict__ P1,
                                               const float* __restrict__ ML, half_t* __restrict__ AO){
    int t   = blockIdx.x * 256 + threadIdx.x;   // 2,097,152 threads
    int row = t >> 4;                           // bh*2048 + s
    int c   = t & 15;
    float m1 = ML[row];
    float l1 = ML[131072 + row];
    float m2 = ML[262144 + row];
    float l2 = ML[393216 + row];
    float M  = fmaxf(m1, m2);
    float w1 = exp2f(m1 - M) * l1;
    float w2 = exp2f(m2 - M) * l2;
    float inv = 1.0f / (w1 + w2);
    float a1 = w1 * inv, a2 = w2 * inv;
    int bh = row >> 11, s = row & 2047;
    int b = bh >> 4, h = bh & 15;
    size_t idx = ((size_t)(b*2048 + s))*2048 + h*128 + c*8;
    half8 x1 = *(const half8*)(P0 + idx);
    half8 x2 = *(const half8*)(P1 + idx);
    half8 o;
#pragma unroll
    for (int j = 0; j < 8; j++)
        o[j] = (half_t)(a1*(float)x1[j] + a2*(float)x2[j]);
    *(half8*)(AO + idx) = o;
}

extern "C" void kernel_launch(void* const* d_in, const int* in_sizes, int n_in,
                              void* d_out, int out_size, void* d_ws, size_t ws_size,
                              hipStream_t stream){
    const float* x  = (const float*)d_in[0];
    const float* cs = (const float*)d_in[1];
    const float* sn = (const float*)d_in[2];
    const float* Wq = (const float*)d_in[3];
    const float* Wk = (const float*)d_in[4];
    const float* Wv = (const float*)d_in[5];
    const float* Wo = (const float*)d_in[6];

    half_t* ws = (half_t*)d_ws;
    half_t* xh = ws;
    half_t* w4 = ws + (size_t)16777216;
    half_t* qw = ws + (size_t)33554432;
    half_t* kw = ws + (size_t)50331648;
    half_t* vt = ws + (size_t)67108864;
    half_t* ao = ws + (size_t)83886080;

    // split-K partial buffers: half-0 reuses xh (dead after QKV GEMM);
    // half-1 + m/l live in d_out (dead until the final O-proj overwrites all of it).
    half_t* p0 = xh;
    half_t* p1 = (half_t*)d_out;
    float*  ml = (float*)((char*)d_out + 33554432);

    cvt_k<<<16384, 256, 0, stream>>>(x, xh, 4194304);
    cvtw_k<<<dim3(4096, 4), 256, 0, stream>>>(Wq, Wk, Wv, Wo, w4);

    gemm_nt<<<dim3(64, 48), 256, 0, stream>>>(xh, w4, qw, kw, vt, nullptr, 0);
    rope_k<<<32768, 256, 0, stream>>>(qw, kw, cs, sn);
    attn_k<<<dim3(32, 64), 256, 0, stream>>>(qw, kw, vt, p0, p1, ml);
    merge_k<<<8192, 256, 0, stream>>>(p0, p1, ml, ao);
    gemm_nt<<<dim3(64, 16), 256, 0, stream>>>(ao, w4 + 12582912, nullptr, nullptr, nullptr,
                                              (float*)d_out, 1);
}

// Round 2
// 733.396 us; speedup vs baseline: 1.1366x; 1.1366x over previous
//
#include <hip/hip_runtime.h>

typedef _Float16 half_t;
typedef __attribute__((ext_vector_type(8))) _Float16 half8;
typedef __attribute__((ext_vector_type(4))) _Float16 half4v;
typedef __attribute__((ext_vector_type(4))) float f32x4;

#define MFMA16(a,b,c) __builtin_amdgcn_mfma_f32_16x16x32_f16((a),(b),(c),0,0,0)

__device__ __forceinline__ void gld_lds16(const half_t* g, half_t* l){
    __builtin_amdgcn_global_load_lds((__attribute__((address_space(1))) void*)(g),
                                     (__attribute__((address_space(3))) void*)(l), 16, 0, 0);
}

// ---------------- fp32 -> fp16 convert ----------------
__global__ __launch_bounds__(256) void cvt_k(const float* __restrict__ s, half_t* __restrict__ d, int n4){
    int i = blockIdx.x * 256 + threadIdx.x;
    if (i < n4){
        float4 v = ((const float4*)s)[i];
        half4v h = { (half_t)v.x, (half_t)v.y, (half_t)v.z, (half_t)v.w };
        ((half4v*)d)[i] = h;
    }
}

__global__ __launch_bounds__(256) void cvtw_k(const float* __restrict__ w0, const float* __restrict__ w1,
                                              const float* __restrict__ w2, const float* __restrict__ w3,
                                              half_t* __restrict__ dst){
    const float* srcs[4] = {w0, w1, w2, w3};
    const float* s = srcs[blockIdx.y];
    int i = blockIdx.x * 256 + threadIdx.x;
    float4 v = ((const float4*)s)[i];
    half4v h = { (half_t)v.x, (half_t)v.y, (half_t)v.z, (half_t)v.w };
    ((half4v*)(dst))[(size_t)blockIdx.y * 1048576 + i] = h;
}

// ---------------- 256x256x64 8-phase NT GEMM (T2+T3+T4+T5) ----------------
// C[m,n] = sum_k A[m,k]*B[n,k], K=2048. 512 thr = 8 waves (2M x 4N), LDS 128KiB.
// Each K-tile (BK=64) split into 4 half-tiles [A-ks0, B-ks0, A-ks1, B-ks1],
// each 16KB stored as [128 physrows][64 halves]: physrow p, phys chunk q holds
// logical (row = p + 128*(c>>2), kchunk = c&3) with c = q ^ (p&7)  -> 8
// consecutive lanes read 8 distinct 16B slots (conflict-free ds_read_b128).
// Schedule: phase (T,j): {8 ds_read_b128; stage half h=q+6; vmcnt(6) at odd j;
// barrier; 16 MFMA (setprio 1); barrier}. Invariants: phase q reads halves
// h<=q+1; vmcnt(6)@odd q guarantees h<=q+3 resident; stage@q writes a region
// last read at q-1 (separated by closing barrier). Tail drains 6->2->0.
#define VMWAIT_(n) asm volatile("s_waitcnt vmcnt(" #n ")" ::: "memory")
#define VMWAIT(n)  VMWAIT_(n)

#define STAGE8(hh) { \
    const int Tt2 = (hh) >> 2, jj2 = (hh) & 3; \
    half_t* db = smem + ((jj2 & 1) << 15) + ((Tt2 & 1) << 14) + ((jj2 >> 1) << 13); \
    const half_t* Gs = ((jj2 & 1) ? Bg : Ag) + Tt2*64 + ((jj2 >> 1) << 5); \
    gld_lds16(Gs + off0, db + d0); \
    gld_lds16(Gs + off1, db + d1); \
}

#define PHASE8(Tt, jj, hh, VMN) { \
    half_t* Ah = smem + (((Tt) & 1) << 14) + (((jj) >> 1) << 13); \
    half_t* Bh = Ah + 32768; \
    half8 af[4], bf[4]; \
    _Pragma("unroll") for (int x = 0; x < 4; x++) af[x] = *(const half8*)(Ah + (((jj)&1)*4 + x)*1024 + cA); \
    _Pragma("unroll") for (int y = 0; y < 4; y++) bf[y] = *(const half8*)(Bh + y*1024 + cB); \
    if ((hh) < 128) STAGE8(hh); \
    if ((jj) & 1) VMWAIT(VMN); \
    asm volatile("s_barrier" ::: "memory"); \
    __builtin_amdgcn_s_setprio(1); \
    _Pragma("unroll") for (int x = 0; x < 4; x++) \
      _Pragma("unroll") for (int y = 0; y < 4; y++) \
        acc[((jj)&1)*4 + x][y] = MFMA16(af[x], bf[y], acc[((jj)&1)*4 + x][y]); \
    __builtin_amdgcn_s_setprio(0); \
    __builtin_amdgcn_sched_barrier(0); \
    asm volatile("s_barrier" ::: "memory"); \
}

__global__ __launch_bounds__(512) void gemm8(const half_t* __restrict__ A, const half_t* __restrict__ B,
                                             half_t* __restrict__ Qw, half_t* __restrict__ Kw,
                                             half_t* __restrict__ Vt, float* __restrict__ Co, int kind){
    const int tid  = threadIdx.x;
    const int lane = tid & 63;
    const int w4   = lane >> 4;
    const int l15  = lane & 15;
    const int l7   = lane & 7;
    const int wav  = tid >> 6;
    const int wavM = wav >> 2;      // 0..1  (M half)
    const int wnq  = wav & 3;       // 0..3  (N quarter)

    // XCD-aware bijective swizzle (both grids are multiples of 8)
    const int nwg = gridDim.x;
    const int wg  = blockIdx.x;
    const int swz = (wg & 7) * (nwg >> 3) + (wg >> 3);
    const int bm  = swz & 31;       // M/256 = 32
    const int bn  = swz >> 5;

    __shared__ __align__(16) half_t smem[65536];   // 128 KiB

    const half_t* Ag = A + (size_t)bm * 256 * 2048;
    const half_t* Bg = B + (size_t)bn * 256 * 2048;

    // staging per-thread constants: cl = tid (+512): p = cl>>3, q = cl&7, c = q^(p&7)
    const int p0  = tid >> 3, q0 = tid & 7, c0 = q0 ^ (p0 & 7);
    const int off0 = (p0 + ((c0 >> 2) << 7)) * 2048 + ((c0 & 3) << 3);
    const int off1 = off0 + 131072;                 // +64 rows * 2048
    const int d0  = tid * 8, d1 = d0 + 4096;

    // fragment read per-thread constants
    const int cA = l15*64 + (((w4 | (wavM << 2)) ^ l7) << 3);
    const int cB = ((wnq & 1)*64 + l15)*64 + (((w4 | ((wnq >> 1) << 2)) ^ l7) << 3);

    f32x4 acc[8][4] = {};

    // prologue: stage halves 0..5, make tile0 resident
#pragma unroll
    for (int h = 0; h < 6; h++) STAGE8(h);
    VMWAIT(4);
    asm volatile("s_barrier" ::: "memory");

    for (int it = 0; it < 15; it++){
        const int h0 = it*8 + 6;
        PHASE8(2*it,   0, h0,     6); PHASE8(2*it,   1, h0 + 1, 6);
        PHASE8(2*it,   2, h0 + 2, 6); PHASE8(2*it,   3, h0 + 3, 6);
        PHASE8(2*it+1, 0, h0 + 4, 6); PHASE8(2*it+1, 1, h0 + 5, 6);
        PHASE8(2*it+1, 2, h0 + 6, 6); PHASE8(2*it+1, 3, h0 + 7, 6);
    }
    // tail iteration (it = 15): last stages are h=126,127; tighten drains
    PHASE8(30, 0, 126, 6); PHASE8(30, 1, 127, 6);
    PHASE8(30, 2, 128, 6); PHASE8(30, 3, 129, 2);
    PHASE8(31, 0, 130, 0); PHASE8(31, 1, 131, 0);
    PHASE8(31, 2, 132, 0); PHASE8(31, 3, 133, 0);

    const int mB = bm*256 + wavM*128 + w4*4;
    const int nB = bn*256 + wnq*64 + l15;

    if (kind == 0){
#pragma unroll
        for (int mi = 0; mi < 8; mi++)
#pragma unroll
            for (int ni = 0; ni < 4; ni++){
                int n  = nB + ni*16;
                int which = n >> 11;
                int nb = n & 2047;
                int m0 = mB + mi*16;
                if (which < 2){
                    half_t* dst = which ? Kw : Qw;
#pragma unroll
                    for (int r = 0; r < 4; r++){
                        int m = m0 + r;
                        dst[(((size_t)(m >> 11)*16 + (nb >> 7))*2048 + (m & 2047))*128 + (nb & 127)] = (half_t)acc[mi][ni][r];
                    }
                } else {
                    half4v hv = {(half_t)acc[mi][ni][0], (half_t)acc[mi][ni][1],
                                 (half_t)acc[mi][ni][2], (half_t)acc[mi][ni][3]};
                    *(half4v*)(Vt + (((size_t)(m0 >> 11)*16 + (nb >> 7))*128 + (nb & 127))*2048 + (m0 & 2047)) = hv;
                }
            }
    } else {
#pragma unroll
        for (int mi = 0; mi < 8; mi++)
#pragma unroll
            for (int ni = 0; ni < 4; ni++){
                int n  = nB + ni*16;
                int m0 = mB + mi*16;
#pragma unroll
                for (int r = 0; r < 4; r++)
                    Co[(size_t)(m0 + r)*2048 + n] = acc[mi][ni][r];
            }
    }
}

// ---------------- RoPE in-place on Q/K [b*16+h][s][128] ----------------
__global__ __launch_bounds__(256) void rope_k(half_t* __restrict__ Qw, half_t* __restrict__ Kw,
                                              const float* __restrict__ cs, const float* __restrict__ sn){
    int t  = blockIdx.x * 256 + threadIdx.x;
    int d  = t & 63;
    int s  = (t >> 6) & 2047;
    int bh = t >> 17;
    float c  = cs[s*64 + d];
    float si = sn[s*64 + d];
    size_t base = ((size_t)bh*2048 + s)*128 + d;
    float q1 = (float)Qw[base], q2 = (float)Qw[base+64];
    Qw[base]    = (half_t)(q1*c - q2*si);
    Qw[base+64] = (half_t)(q1*si + q2*c);
    float k1 = (float)Kw[base], k2 = (float)Kw[base+64];
    Kw[base]    = (half_t)(k1*c - k2*si);
    Kw[base+64] = (half_t)(k1*si + k2*c);
}

// ---------------- Flash attention, S^T formulation ----------------
// Q[bh][s][128], K[bh][s][128], Vt[bh][128][s] -> AO [b*2048+s][h*128+d]
__global__ __launch_bounds__(256, 3) void attn_k(const half_t* __restrict__ Q, const half_t* __restrict__ K,
                                                 const half_t* __restrict__ Vt, half_t* __restrict__ AO){
    const int tid  = threadIdx.x;
    const int lane = tid & 63;
    const int w    = lane >> 4;
    const int l15  = lane & 15;
    const int l7   = lane & 7;
    const int wav  = tid >> 6;
    const int qt   = blockIdx.x;   // 16 q-tiles of 128
    const int bh   = blockIdx.y;   // 64

    // Ks 16KB | Vs 16KB | Ps 4 x (32x72) 18KB. Ob overlays Ks+Vs after K loop.
    __shared__ __align__(16) half_t smem[8192 + 8192 + 4*2304];
    half_t* Ks = smem;
    half_t* Vs = smem + 8192;
    half_t* Ps = smem + 16384 + wav*2304;
    half_t* Ob = smem + wav*4096;

    const half_t* Qb = Q + ((size_t)bh*2048 + qt*128 + wav*32)*128;
    half8 aq[2][4];
#pragma unroll
    for (int qi = 0; qi < 2; qi++)
#pragma unroll
        for (int ks = 0; ks < 4; ks++)
            aq[qi][ks] = *(const half8*)(Qb + (qi*16 + l15)*128 + ks*32 + w*8);

    f32x4 oacc[8][2] = {};
    float m_[2] = {-1e30f, -1e30f};
    float l_[2] = {0.0f, 0.0f};

    const float SSC = 0.08838834764831845f * 1.4426950408889634f;  // 1/sqrt(128) * log2(e)

    for (int kt = 0; kt < 32; kt++){
        const half_t* Kb = K  + ((size_t)bh*2048 + kt*64)*128;
        const half_t* Vb = Vt + (size_t)bh*128*2048 + kt*64;
        __syncthreads();
#pragma unroll
        for (int i = 0; i < 4; i++){
            int c = tid + i*256;
            int key = c >> 4, pc = c & 15;
            gld_lds16(Kb + key*128 + ((pc ^ (key&7)) << 3), Ks + c*8);
        }
#pragma unroll
        for (int i = 0; i < 4; i++){
            int c = tid + i*256;
            int d = c >> 3, pc = c & 7;
            gld_lds16(Vb + (size_t)d*2048 + ((pc ^ (d&7)) << 3), Vs + c*8);
        }
        __syncthreads();

        // S^T = K @ Q^T : rows=key (4 tiles), cols=q (2 tiles)
        f32x4 sacc[4][2] = {};
#pragma unroll
        for (int ks = 0; ks < 4; ks++){
#pragma unroll
            for (int t = 0; t < 4; t++){
                half8 kf = *(const half8*)(Ks + (t*16 + l15)*128 + (((ks*4 + w) ^ l7) << 3));
                sacc[t][0] = MFMA16(kf, aq[0][ks], sacc[t][0]);
                sacc[t][1] = MFMA16(kf, aq[1][ks], sacc[t][1]);
            }
        }

        // online softmax per q-column; defer-max: skip rescale when no column max grew (exact)
#pragma unroll
        for (int qi = 0; qi < 2; qi++){
            float mx = sacc[0][qi][0];
#pragma unroll
            for (int t = 0; t < 4; t++)
#pragma unroll
                for (int r = 0; r < 4; r++) mx = fmaxf(mx, sacc[t][qi][r]);
            mx = fmaxf(mx, __shfl_xor(mx, 16));
            mx = fmaxf(mx, __shfl_xor(mx, 32));
            float mxs = mx * SSC;
            unsigned long long upd = __ballot(mxs > m_[qi]);
            if (upd){
                float mn    = fmaxf(m_[qi], mxs);
                float alpha = exp2f(m_[qi] - mn);
                m_[qi] = mn;
                l_[qi] *= alpha;
#pragma unroll
                for (int t = 0; t < 8; t++)
#pragma unroll
                    for (int r = 0; r < 4; r++) oacc[t][qi][r] *= alpha;
            }
            float mq = m_[qi];
            float sum = 0.0f;
#pragma unroll
            for (int t = 0; t < 4; t++){
                float p0 = exp2f(sacc[t][qi][0]*SSC - mq);
                float p1 = exp2f(sacc[t][qi][1]*SSC - mq);
                float p2 = exp2f(sacc[t][qi][2]*SSC - mq);
                float p3 = exp2f(sacc[t][qi][3]*SSC - mq);
                sum += (p0 + p1) + (p2 + p3);
                half4v hv = {(half_t)p0, (half_t)p1, (half_t)p2, (half_t)p3};
                *(half4v*)(Ps + (qi*16 + l15)*72 + t*16 + w*4) = hv;
            }
            sum += __shfl_xor(sum, 16);
            sum += __shfl_xor(sum, 32);
            l_[qi] += sum;
        }

        // O^T += V^T @ P^T
#pragma unroll
        for (int c2 = 0; c2 < 2; c2++){
            half8 pf0 = *(const half8*)(Ps + l15*72        + c2*32 + w*8);
            half8 pf1 = *(const half8*)(Ps + (16 + l15)*72 + c2*32 + w*8);
#pragma unroll
            for (int t = 0; t < 8; t++){
                half8 vf = *(const half8*)(Vs + (t*16 + l15)*64 + (((c2*4 + w) ^ l7) << 3));
                oacc[t][0] = MFMA16(vf, pf0, oacc[t][0]);
                oacc[t][1] = MFMA16(vf, pf1, oacc[t][1]);
            }
        }
    }

    // epilogue: transpose O^T -> O through LDS, coalesced global stores
    float inv[2] = {1.0f / l_[0], 1.0f / l_[1]};
    __syncthreads();
#pragma unroll
    for (int t = 0; t < 8; t++)
#pragma unroll
        for (int qi = 0; qi < 2; qi++){
            int q  = qi*16 + l15;
            int c8 = t*2 + (w>>1);
            int pc = c8 ^ l7;
            half4v hv = {(half_t)(oacc[t][qi][0]*inv[qi]), (half_t)(oacc[t][qi][1]*inv[qi]),
                         (half_t)(oacc[t][qi][2]*inv[qi]), (half_t)(oacc[t][qi][3]*inv[qi])};
            *(half4v*)(Ob + q*128 + pc*8 + (w&1)*4) = hv;
        }
    const int b = bh >> 4, h = bh & 15;
#pragma unroll
    for (int it = 0; it < 8; it++){
        int q  = it*4 + w;
        half8 rd = *(const half8*)(Ob + q*128 + ((l15 ^ (q&7)) << 3));
        int s = qt*128 + wav*32 + q;
        *(half8*)(AO + ((size_t)(b*2048 + s))*2048 + h*128 + l15*8) = rd;
    }
}

extern "C" void kernel_launch(void* const* d_in, const int* in_sizes, int n_in,
                              void* d_out, int out_size, void* d_ws, size_t ws_size,
                              hipStream_t stream){
    const float* x  = (const float*)d_in[0];
    const float* cs = (const float*)d_in[1];
    const float* sn = (const float*)d_in[2];
    const float* Wq = (const float*)d_in[3];
    const float* Wk = (const float*)d_in[4];
    const float* Wv = (const float*)d_in[5];
    const float* Wo = (const float*)d_in[6];

    half_t* ws = (half_t*)d_ws;
    half_t* xh = ws;
    half_t* w4 = ws + (size_t)16777216;
    half_t* qw = ws + (size_t)33554432;
    half_t* kw = ws + (size_t)50331648;
    half_t* vt = ws + (size_t)67108864;
    half_t* ao = ws + (size_t)83886080;

    cvt_k<<<16384, 256, 0, stream>>>(x, xh, 4194304);
    cvtw_k<<<dim3(4096, 4), 256, 0, stream>>>(Wq, Wk, Wv, Wo, w4);

    gemm8<<<768, 512, 0, stream>>>(xh, w4, qw, kw, vt, nullptr, 0);
    rope_k<<<32768, 256, 0, stream>>>(qw, kw, cs, sn);
    attn_k<<<dim3(16, 64), 256, 0, stream>>>(qw, kw, vt, ao);
    gemm8<<<256, 512, 0, stream>>>(ao, w4 + 12582912, nullptr, nullptr, nullptr,
                                   (float*)d_out, 1);
}